// Round 1
// baseline (141.611 us; speedup 1.0000x reference)
//
#include <hip/hip_runtime.h>
#include <hip/hip_bf16.h>
#include <math.h>

#define N 4096
#define D 128
#define NJ 4
#define KTOP 16
#define CSPLIT 2

typedef __attribute__((ext_vector_type(8))) short bf16x8;
typedef __attribute__((ext_vector_type(4))) float f32x4;

// ws layout:
//   [0, 1MB)   fh   bf16 [N][D]       normalized feature rows, row-major
//   [1MB, 5MB) gh   bf16 [NJ][N*D]    normalized negative rows, FRAGMENT-MAJOR
//   [5MB, 7MB) top  f32  [NJ][N][CSPLIT][16] partial sorted top-16 per col-split

__device__ __forceinline__ void ce_desc(float* a, int i, int l) {
    float x = a[i], y = a[l];
    a[i] = fmaxf(x, y);
    a[l] = fminf(x, y);
}

// Batcher odd-even mergesort of 16 (descending), 63 compare-exchanges
// (vs 80 for bitonic). Derived from the recursive construction:
// sort(0,8); sort(8,8); oddEvenMerge(0,16,1).
__device__ __forceinline__ void sort16_desc(float* a) {
    // sort(0,8)
    ce_desc(a,0,1);  ce_desc(a,2,3);  ce_desc(a,0,2);  ce_desc(a,1,3);  ce_desc(a,1,2);
    ce_desc(a,4,5);  ce_desc(a,6,7);  ce_desc(a,4,6);  ce_desc(a,5,7);  ce_desc(a,5,6);
    ce_desc(a,0,4);  ce_desc(a,2,6);  ce_desc(a,2,4);  ce_desc(a,1,5);  ce_desc(a,3,7);
    ce_desc(a,3,5);  ce_desc(a,1,2);  ce_desc(a,3,4);  ce_desc(a,5,6);
    // sort(8,8)
    ce_desc(a,8,9);  ce_desc(a,10,11); ce_desc(a,8,10); ce_desc(a,9,11); ce_desc(a,9,10);
    ce_desc(a,12,13); ce_desc(a,14,15); ce_desc(a,12,14); ce_desc(a,13,15); ce_desc(a,13,14);
    ce_desc(a,8,12); ce_desc(a,10,14); ce_desc(a,10,12); ce_desc(a,9,13); ce_desc(a,11,15);
    ce_desc(a,11,13); ce_desc(a,9,10); ce_desc(a,11,12); ce_desc(a,13,14);
    // oddEvenMerge(0,16,1)
    ce_desc(a,0,8);  ce_desc(a,4,12); ce_desc(a,4,8);  ce_desc(a,2,10); ce_desc(a,6,14);
    ce_desc(a,6,10); ce_desc(a,2,4);  ce_desc(a,6,8);  ce_desc(a,10,12);
    ce_desc(a,1,9);  ce_desc(a,5,13); ce_desc(a,5,9);  ce_desc(a,3,11); ce_desc(a,7,15);
    ce_desc(a,7,11); ce_desc(a,3,5);  ce_desc(a,7,9);  ce_desc(a,11,13);
    ce_desc(a,1,2);  ce_desc(a,3,4);  ce_desc(a,5,6);  ce_desc(a,7,8);  ce_desc(a,9,10);
    ce_desc(a,11,12); ce_desc(a,13,14);
}

// clean a bitonic 16-sequence into descending order (32 CE)
__device__ __forceinline__ void bitonic_clean16_desc(float* a) {
    #pragma unroll
    for (int jj = 8; jj > 0; jj >>= 1) {
        #pragma unroll
        for (int i = 0; i < 16; i++) {
            int l = i ^ jj;
            if (l > i) {
                float x = a[i], y = a[l];
                a[i] = fmaxf(x, y);
                a[l] = fminf(x, y);
            }
        }
    }
}

// ---------------- prep: fp32 L2-normalize -> bf16, negs to fragment-major ----------------
__global__ __launch_bounds__(256) void neguni_prep(
    const float* __restrict__ feat, const float* __restrict__ negs,
    unsigned short* __restrict__ fh, unsigned short* __restrict__ gh)
{
    const int w    = threadIdx.x >> 6;
    const int lane = threadIdx.x & 63;
    const int p    = lane & 15;                    // piece 0..15
    const int rr   = lane >> 4;                    // row within wave
    const int row  = blockIdx.x * 16 + w * 4 + rr; // 0..20479

    const float* src = (row < N) ? (feat + (size_t)row * D)
                                 : (negs + (size_t)(row - N) * D);
    float4 v0 = ((const float4*)src)[p * 2];
    float4 v1 = ((const float4*)src)[p * 2 + 1];
    float ss = v0.x*v0.x + v0.y*v0.y + v0.z*v0.z + v0.w*v0.w
             + v1.x*v1.x + v1.y*v1.y + v1.z*v1.z + v1.w*v1.w;
    ss += __shfl_xor(ss, 1, 64);
    ss += __shfl_xor(ss, 2, 64);
    ss += __shfl_xor(ss, 4, 64);
    ss += __shfl_xor(ss, 8, 64);
    const float inv = 1.0f / fmaxf(sqrtf(ss), 1e-12f);

    float f[8] = {v0.x, v0.y, v0.z, v0.w, v1.x, v1.y, v1.z, v1.w};
    unsigned int u[4];
    #pragma unroll
    for (int i = 0; i < 4; i++) {
        __hip_bfloat16 b0 = __float2bfloat16(f[2*i]   * inv);
        __hip_bfloat16 b1 = __float2bfloat16(f[2*i+1] * inv);
        u[i] = ((unsigned int)*(unsigned short*)&b1 << 16) | *(unsigned short*)&b0;
    }
    uint4 pk; pk.x = u[0]; pk.y = u[1]; pk.z = u[2]; pk.w = u[3];

    if (row < N) {
        *(uint4*)(fh + (size_t)row * D + p * 8) = pk;          // row-major
    } else {
        const int rn  = row - N;
        const int j   = rn >> 12;
        const int rj  = rn & 4095;
        const int chg = rj >> 6;       // 64-cand chunk
        const int cl  = rj & 63;
        const int t   = cl >> 4;
        const int col = cl & 15;
        const int s   = p >> 2;
        const int q   = p & 3;
        *(uint4*)(gh + (size_t)j * N * D + (size_t)chg * 8192
                  + (s * 4 + t) * 512 + (q * 16 + col) * 8) = pk;
    }
}

// ---------------- main: pipelined transposed MFMA + lane-local batched top-16 ----------------
// Software pipeline: per chunk iteration, issue NEXT chunk's 16 A-frag loads first,
// then sort/merge the CURRENT chunk (hides L2 latency under ~500 cy of sort VALU),
// then run next chunk's MFMAs at the bottom (vmcnt satisfied, results read next iter).
__global__ __launch_bounds__(256) void neguni_main(
    const unsigned short* __restrict__ fh, const unsigned short* __restrict__ gh,
    const int* __restrict__ target, const int* __restrict__ idxp,
    float* __restrict__ topbuf)
{
    __shared__ float tops[4][16][17];

    const int tid   = threadIdx.x;
    const int w     = tid >> 6;
    const int lane  = tid & 63;
    const int col16 = lane & 15;     // feature row within tile
    const int quad  = lane >> 4;

    const int j   = blockIdx.x & 3;
    const int ft  = (blockIdx.x >> 2) & 255;
    const int cs  = blockIdx.x >> 10;
    const int r0  = ft * 16;
    const int c0  = cs * 2048 + w * 512;
    const int idx = idxp[0];
    const bool msk = (j == idx);

    // B fragments: 16 feature rows, persistent
    bf16x8 bfr[4];
    {
        const unsigned short* fr = fh + (size_t)(r0 + col16) * D + quad * 8;
        bfr[0] = *(const bf16x8*)(fr);
        bfr[1] = *(const bf16x8*)(fr + 32);
        bfr[2] = *(const bf16x8*)(fr + 64);
        bfr[3] = *(const bf16x8*)(fr + 96);
    }
    const int rtg = target[r0 + col16];

    const int chg0 = cs * 32 + w * 8;
    const unsigned short* ab0 = gh + (size_t)j * N * D + (size_t)chg0 * 8192 + lane * 8;

    float lst[KTOP];
    f32x4 acc[4];

    // prologue: chunk 0 loads + MFMA
    {
        bf16x8 fA[16];
        #pragma unroll
        for (int u = 0; u < 16; u++) fA[u] = *(const bf16x8*)(ab0 + u * 512);
        #pragma unroll
        for (int t = 0; t < 4; t++) acc[t] = (f32x4){0.f, 0.f, 0.f, 0.f};
        #pragma unroll
        for (int s = 0; s < 4; s++) {
            #pragma unroll
            for (int t = 0; t < 4; t++)
                acc[t] = __builtin_amdgcn_mfma_f32_16x16x32_bf16(fA[s * 4 + t], bfr[s], acc[t], 0, 0, 0);
        }
    }

    #pragma unroll 1
    for (int ch = 0; ch < 7; ch++) {
        // ---- prefetch next chunk's A fragments (issue before the sort) ----
        bf16x8 fB[16];
        {
            const unsigned short* ab = ab0 + (size_t)(ch + 1) * 8192;
            #pragma unroll
            for (int u = 0; u < 16; u++) fB[u] = *(const bf16x8*)(ab + u * 512);
        }
        __builtin_amdgcn_sched_barrier(0);   // keep loads above the sort

        // ---- gather + mask current chunk ----
        const int cbase = c0 + ch * 64;
        float s16[16];
        #pragma unroll
        for (int t = 0; t < 4; t++) {
            s16[t * 4 + 0] = acc[t][0];
            s16[t * 4 + 1] = acc[t][1];
            s16[t * 4 + 2] = acc[t][2];
            s16[t * 4 + 3] = acc[t][3];
        }
        if (msk) {
            #pragma unroll
            for (int t = 0; t < 4; t++) {
                int4 tc = *(const int4*)(target + cbase + t * 16 + quad * 4);
                if (tc.x == rtg) s16[t * 4 + 0] = -1e9f;
                if (tc.y == rtg) s16[t * 4 + 1] = -1e9f;
                if (tc.z == rtg) s16[t * 4 + 2] = -1e9f;
                if (tc.w == rtg) s16[t * 4 + 3] = -1e9f;
            }
        }

        // ---- sort + merge (hides the fB loads) ----
        sort16_desc(s16);
        if (ch == 0) {
            #pragma unroll
            for (int i = 0; i < 16; i++) lst[i] = s16[i];
        } else {
            float mg[16];
            #pragma unroll
            for (int i = 0; i < 16; i++) mg[i] = fmaxf(lst[i], s16[15 - i]);
            bitonic_clean16_desc(mg);
            #pragma unroll
            for (int i = 0; i < 16; i++) lst[i] = mg[i];
        }

        // ---- next chunk's MFMAs at the bottom ----
        #pragma unroll
        for (int t = 0; t < 4; t++) acc[t] = (f32x4){0.f, 0.f, 0.f, 0.f};
        #pragma unroll
        for (int s = 0; s < 4; s++) {
            #pragma unroll
            for (int t = 0; t < 4; t++)
                acc[t] = __builtin_amdgcn_mfma_f32_16x16x32_bf16(fB[s * 4 + t], bfr[s], acc[t], 0, 0, 0);
        }
    }

    // epilogue: chunk 7 (no prefetch)
    {
        const int cbase = c0 + 7 * 64;
        float s16[16];
        #pragma unroll
        for (int t = 0; t < 4; t++) {
            s16[t * 4 + 0] = acc[t][0];
            s16[t * 4 + 1] = acc[t][1];
            s16[t * 4 + 2] = acc[t][2];
            s16[t * 4 + 3] = acc[t][3];
        }
        if (msk) {
            #pragma unroll
            for (int t = 0; t < 4; t++) {
                int4 tc = *(const int4*)(target + cbase + t * 16 + quad * 4);
                if (tc.x == rtg) s16[t * 4 + 0] = -1e9f;
                if (tc.y == rtg) s16[t * 4 + 1] = -1e9f;
                if (tc.z == rtg) s16[t * 4 + 2] = -1e9f;
                if (tc.w == rtg) s16[t * 4 + 3] = -1e9f;
            }
        }
        sort16_desc(s16);
        float mg[16];
        #pragma unroll
        for (int i = 0; i < 16; i++) mg[i] = fmaxf(lst[i], s16[15 - i]);
        bitonic_clean16_desc(mg);
        #pragma unroll
        for (int i = 0; i < 16; i++) lst[i] = mg[i];
    }

    // intra-wave merge across quads (lanes with same col16): 2 shfl levels
    #pragma unroll
    for (int off = 16; off <= 32; off <<= 1) {
        float mg[16];
        #pragma unroll
        for (int i = 0; i < 16; i++)
            mg[i] = fmaxf(lst[i], __shfl_xor(lst[15 - i], off, 64));
        bitonic_clean16_desc(mg);
        #pragma unroll
        for (int i = 0; i < 16; i++) lst[i] = mg[i];
    }

    if (lane < 16) {
        #pragma unroll
        for (int i = 0; i < 16; i++) tops[w][lane][i] = lst[i];
        tops[w][lane][16] = -3.0e38f;   // sentinel
    }
    __syncthreads();

    // cross-wave 4-way serial merge (waves cover disjoint candidate ranges)
    if (tid < 16) {
        int i0 = 0, i1 = 0, i2 = 0, i3 = 0;
        float* outp = topbuf + (((size_t)j * N + r0 + tid) * CSPLIT + cs) * KTOP;
        #pragma unroll
        for (int k = 0; k < KTOP; k++) {
            float v0 = tops[0][tid][i0], v1 = tops[1][tid][i1];
            float v2 = tops[2][tid][i2], v3 = tops[3][tid][i3];
            float m01 = fmaxf(v0, v1), m23 = fmaxf(v2, v3);
            float mx  = fmaxf(m01, m23);
            if      (mx == v0) i0++;
            else if (mx == v1) i1++;
            else if (mx == v2) i2++;
            else               i3++;
            outp[k] = mx;
        }
    }
}

// ---------------- finalize: 2-way merge of partials + entropy reduce ----------------
// 256 blocks x 1 wave (16 rows/block): 4x the parallelism of the old 64-block version,
// powf eliminated (decay via __expf), fast transcendentals.
__global__ __launch_bounds__(64) void neguni_fin(
    const float* __restrict__ topbuf, float* __restrict__ out)
{
    __shared__ float buf[64][35];     // 2 lists of 17 (16 + sentinel) per thread
    __shared__ float mm[16][65];      // merged [row_l][k*4+j], padded

    const int t     = threadIdx.x;    // 0..63
    const int j     = t >> 4;         // 0..3
    const int row_l = t & 15;         // 0..15
    const int row   = blockIdx.x * 16 + row_l;

    const float4* src = (const float4*)(topbuf + ((size_t)j * N + row) * (CSPLIT * KTOP));
    #pragma unroll
    for (int q = 0; q < 8; q++) {
        float4 v = src[q];
        const int base = (q >> 2) * 17 + (q & 3) * 4;
        buf[t][base + 0] = v.x;
        buf[t][base + 1] = v.y;
        buf[t][base + 2] = v.z;
        buf[t][base + 3] = v.w;
    }
    buf[t][16] = -3.0e38f;
    buf[t][33] = -3.0e38f;

    {
        int ia = 0, ib = 17;
        #pragma unroll
        for (int k = 0; k < KTOP; k++) {
            float va = buf[t][ia], vb = buf[t][ib];
            bool ta = va >= vb;
            mm[row_l][k * 4 + j] = ta ? va : vb;
            if (ta) ia++; else ib++;
        }
    }
    __syncthreads();

    float val = 0.f;
    #pragma unroll
    for (int i = 0; i < 4; i++) {
        const int idx2 = t + i * 64;          // 0..255
        const int rl   = idx2 & 15;
        const int k    = idx2 >> 4;           // 0..15
        float l0 = mm[rl][k * 4 + 0] * 100.0f;
        float l1 = mm[rl][k * 4 + 1] * 100.0f;
        float l2 = mm[rl][k * 4 + 2] * 100.0f;
        float l3 = mm[rl][k * 4 + 3] * 100.0f;
        float m  = fmaxf(fmaxf(l0, l1), fmaxf(l2, l3));
        float d0 = l0 - m, d1 = l1 - m, d2 = l2 - m, d3 = l3 - m;
        float e0 = __expf(d0), e1 = __expf(d1), e2 = __expf(d2), e3 = __expf(d3);
        float s  = e0 + e1 + e2 + e3;
        float ent = (e0 * d0 + e1 * d1 + e2 * d2 + e3 * d3) / s - __logf(s);
        float dk  = __expf(-0.05129329439f * (float)k);   // 0.95^k
        val += ent * dk;
    }
    val *= (1.0f / (11.1974666f * (float)N));   // Ssum = (1-0.95^16)/0.05

    #pragma unroll
    for (int off = 32; off > 0; off >>= 1) val += __shfl_xor(val, off, 64);
    if (t == 0) {
        atomicAdd(out, val);
        if (blockIdx.x == 0) atomicAdd(out, 1.38629436112f);   // log(4)
    }
}

extern "C" void kernel_launch(void* const* d_in, const int* in_sizes, int n_in,
                              void* d_out, int out_size, void* d_ws, size_t ws_size,
                              hipStream_t stream) {
    const float* feat   = (const float*)d_in[0];
    const int*   target = (const int*)d_in[1];
    const float* negs   = (const float*)d_in[2];
    const int*   idxp   = (const int*)d_in[3];
    float* out = (float*)d_out;

    unsigned short* fh = (unsigned short*)d_ws;
    unsigned short* gh = fh + (size_t)N * D;                  // +1 MB
    float* topbuf      = (float*)(gh + (size_t)NJ * N * D);   // +5 MB, 2 MB long

    hipMemsetAsync(out, 0, sizeof(float), stream);
    neguni_prep<<<dim3((N + NJ * N) / 16), dim3(256), 0, stream>>>(feat, negs, fh, gh);
    neguni_main<<<dim3(NJ * (N / 16) * CSPLIT), dim3(256), 0, stream>>>(fh, gh, target, idxp, topbuf);
    neguni_fin<<<dim3(N / 16), dim3(64), 0, stream>>>(topbuf, out);
}

// Round 2
// 134.189 us; speedup vs baseline: 1.0553x; 1.0553x over previous
//
#include <hip/hip_runtime.h>
#include <hip/hip_bf16.h>
#include <math.h>

#define N 4096
#define D 128
#define NJ 4
#define KTOP 16
#define CSPLIT 2

typedef __attribute__((ext_vector_type(8))) short bf16x8;
typedef __attribute__((ext_vector_type(4))) float f32x4;

// ws layout:
//   [0, 1MB)   fh   bf16 [N][D]       normalized feature rows, row-major
//   [1MB, 5MB) gh   bf16 [NJ][N*D]    normalized negative rows, FRAGMENT-MAJOR:
//              per j, per 64-cand chunk chg (64 chunks): 16 frags x 512 ushorts.
//   [5MB, 7MB) top  f32  [NJ][N][CSPLIT][16] partial sorted top-16 per col-split

__device__ __forceinline__ void ce_desc(float* a, int i, int l) {
    float x = a[i], y = a[l];
    a[i] = fmaxf(x, y);
    a[l] = fminf(x, y);
}

// Batcher odd-even mergesort of 16 (descending), 63 compare-exchanges.
// Harness-verified in round 1 (absmax 0.0).
__device__ __forceinline__ void sort16_desc(float* a) {
    // sort(0,8)
    ce_desc(a,0,1);  ce_desc(a,2,3);  ce_desc(a,0,2);  ce_desc(a,1,3);  ce_desc(a,1,2);
    ce_desc(a,4,5);  ce_desc(a,6,7);  ce_desc(a,4,6);  ce_desc(a,5,7);  ce_desc(a,5,6);
    ce_desc(a,0,4);  ce_desc(a,2,6);  ce_desc(a,2,4);  ce_desc(a,1,5);  ce_desc(a,3,7);
    ce_desc(a,3,5);  ce_desc(a,1,2);  ce_desc(a,3,4);  ce_desc(a,5,6);
    // sort(8,8)
    ce_desc(a,8,9);  ce_desc(a,10,11); ce_desc(a,8,10); ce_desc(a,9,11); ce_desc(a,9,10);
    ce_desc(a,12,13); ce_desc(a,14,15); ce_desc(a,12,14); ce_desc(a,13,15); ce_desc(a,13,14);
    ce_desc(a,8,12); ce_desc(a,10,14); ce_desc(a,10,12); ce_desc(a,9,13); ce_desc(a,11,15);
    ce_desc(a,11,13); ce_desc(a,9,10); ce_desc(a,11,12); ce_desc(a,13,14);
    // oddEvenMerge(0,16,1)
    ce_desc(a,0,8);  ce_desc(a,4,12); ce_desc(a,4,8);  ce_desc(a,2,10); ce_desc(a,6,14);
    ce_desc(a,6,10); ce_desc(a,2,4);  ce_desc(a,6,8);  ce_desc(a,10,12);
    ce_desc(a,1,9);  ce_desc(a,5,13); ce_desc(a,5,9);  ce_desc(a,3,11); ce_desc(a,7,15);
    ce_desc(a,7,11); ce_desc(a,3,5);  ce_desc(a,7,9);  ce_desc(a,11,13);
    ce_desc(a,1,2);  ce_desc(a,3,4);  ce_desc(a,5,6);  ce_desc(a,7,8);  ce_desc(a,9,10);
    ce_desc(a,11,12); ce_desc(a,13,14);
}

// clean a bitonic 16-sequence into descending order (32 CE)
__device__ __forceinline__ void bitonic_clean16_desc(float* a) {
    #pragma unroll
    for (int jj = 8; jj > 0; jj >>= 1) {
        #pragma unroll
        for (int i = 0; i < 16; i++) {
            int l = i ^ jj;
            if (l > i) {
                float x = a[i], y = a[l];
                a[i] = fmaxf(x, y);
                a[l] = fminf(x, y);
            }
        }
    }
}

// ---------------- prep: fp32 L2-normalize -> bf16 ----------------
// blocks 0..255   : feature rows, row-major fh (coalesced, as before)
// blocks 256..511 : one 64-row negative chunk each; LDS-staged transpose to
//                   fragment-major, then ONE contiguous 16KB coalesced stream out.
//                   (old version: 64 scattered 16B stores per wave = 4x transaction
//                   amplification on a 4MB buffer)
__global__ __launch_bounds__(256) void neguni_prep(
    const float* __restrict__ feat, const float* __restrict__ negs,
    unsigned short* __restrict__ fh, unsigned short* __restrict__ gh,
    float* __restrict__ out)
{
    __shared__ unsigned short lbuf[8192];   // 16KB chunk staging

    if (blockIdx.x == 0 && threadIdx.x == 0) *out = 0.f;   // replaces memset dispatch

    if (blockIdx.x < 256) {
        // ---- feature rows: 16 lanes per row, 4 rows per wave ----
        const int w    = threadIdx.x >> 6;
        const int lane = threadIdx.x & 63;
        const int p    = lane & 15;
        const int rr   = lane >> 4;
        const int row  = blockIdx.x * 16 + w * 4 + rr;   // 0..4095

        const float* src = feat + (size_t)row * D;
        float4 v0 = ((const float4*)src)[p * 2];
        float4 v1 = ((const float4*)src)[p * 2 + 1];
        float ss = v0.x*v0.x + v0.y*v0.y + v0.z*v0.z + v0.w*v0.w
                 + v1.x*v1.x + v1.y*v1.y + v1.z*v1.z + v1.w*v1.w;
        ss += __shfl_xor(ss, 1, 64);
        ss += __shfl_xor(ss, 2, 64);
        ss += __shfl_xor(ss, 4, 64);
        ss += __shfl_xor(ss, 8, 64);
        const float inv = 1.0f / fmaxf(sqrtf(ss), 1e-12f);

        float f[8] = {v0.x, v0.y, v0.z, v0.w, v1.x, v1.y, v1.z, v1.w};
        unsigned int u[4];
        #pragma unroll
        for (int i = 0; i < 4; i++) {
            __hip_bfloat16 b0 = __float2bfloat16(f[2*i]   * inv);
            __hip_bfloat16 b1 = __float2bfloat16(f[2*i+1] * inv);
            u[i] = ((unsigned int)*(unsigned short*)&b1 << 16) | *(unsigned short*)&b0;
        }
        uint4 pk; pk.x = u[0]; pk.y = u[1]; pk.z = u[2]; pk.w = u[3];
        *(uint4*)(fh + (size_t)row * D + p * 8) = pk;
    } else {
        // ---- negative chunk: 64 rows, 4 threads per row (32 floats each) ----
        const int c   = blockIdx.x - 256;    // 0..255
        const int j   = c >> 6;
        const int chg = c & 63;
        const int t   = threadIdx.x;
        const int lr  = t >> 2;              // local row 0..63
        const int p4  = t & 3;               // 32-float piece within row

        const float* src = negs + ((size_t)(j * 4096 + chg * 64 + lr)) * D + p4 * 32;
        float4 v[8];
        float ss = 0.f;
        #pragma unroll
        for (int i = 0; i < 8; i++) {
            v[i] = ((const float4*)src)[i];
            ss += v[i].x*v[i].x + v[i].y*v[i].y + v[i].z*v[i].z + v[i].w*v[i].w;
        }
        ss += __shfl_xor(ss, 1, 64);
        ss += __shfl_xor(ss, 2, 64);
        const float inv = 1.0f / fmaxf(sqrtf(ss), 1e-12f);

        float f[32];
        #pragma unroll
        for (int i = 0; i < 8; i++) {
            f[4*i]   = v[i].x; f[4*i+1] = v[i].y;
            f[4*i+2] = v[i].z; f[4*i+3] = v[i].w;
        }

        const int t16 = lr >> 4;             // t-index of fragment layout
        const int col = lr & 15;
        #pragma unroll
        for (int qq = 0; qq < 4; qq++) {     // piece p = p4*4+qq; s=p4, q=qq
            unsigned int uu[4];
            #pragma unroll
            for (int h = 0; h < 4; h++) {
                __hip_bfloat16 b0 = __float2bfloat16(f[qq*8 + 2*h]     * inv);
                __hip_bfloat16 b1 = __float2bfloat16(f[qq*8 + 2*h + 1] * inv);
                uu[h] = ((unsigned int)*(unsigned short*)&b1 << 16) | *(unsigned short*)&b0;
            }
            uint4 pk; pk.x = uu[0]; pk.y = uu[1]; pk.z = uu[2]; pk.w = uu[3];
            *(uint4*)(lbuf + (p4 * 4 + t16) * 512 + (qq * 16 + col) * 8) = pk;
        }
        __syncthreads();

        // contiguous 16KB stream out: 4 x dwordx4 per thread, fully coalesced
        uint4* dst = (uint4*)(gh + (size_t)j * N * D + (size_t)chg * 8192);
        const uint4* sb = (const uint4*)lbuf;
        dst[t]       = sb[t];
        dst[t + 256] = sb[t + 256];
        dst[t + 512] = sb[t + 512];
        dst[t + 768] = sb[t + 768];
    }
}

// ---------------- main: transposed MFMA + lane-local batched top-16 ----------------
// Round-0 structure (loads+MFMA interleaved by compiler, sort after), which relied
// on TLP: round-1's explicit pipeline (+32 VGPR buffer) halved occupancy and lost 8%.
// __launch_bounds__(256,4): VGPR budget 128 so the sort arrays live in real VGPRs
// instead of AGPR-shuffled spill (VGPR_Count=48 was below the true live set).
__global__ __launch_bounds__(256, 4) void neguni_main(
    const unsigned short* __restrict__ fh, const unsigned short* __restrict__ gh,
    const int* __restrict__ target, const int* __restrict__ idxp,
    float* __restrict__ topbuf)
{
    __shared__ float tops[4][16][17];

    const int tid   = threadIdx.x;
    const int w     = tid >> 6;
    const int lane  = tid & 63;
    const int col16 = lane & 15;     // feature row within tile
    const int quad  = lane >> 4;

    const int j   = blockIdx.x & 3;
    const int ft  = (blockIdx.x >> 2) & 255;
    const int cs  = blockIdx.x >> 10;
    const int r0  = ft * 16;
    const int c0  = cs * 2048 + w * 512;
    const int idx = idxp[0];
    const bool msk = (j == idx);

    // B fragments: 16 feature rows, persistent
    bf16x8 bfr[4];
    {
        const unsigned short* fr = fh + (size_t)(r0 + col16) * D + quad * 8;
        bfr[0] = *(const bf16x8*)(fr);
        bfr[1] = *(const bf16x8*)(fr + 32);
        bfr[2] = *(const bf16x8*)(fr + 64);
        bfr[3] = *(const bf16x8*)(fr + 96);
    }
    const int rtg = target[r0 + col16];

    float lst[KTOP];

    const int chg0 = cs * 32 + w * 8;
    const unsigned short* ab0 = gh + (size_t)j * N * D + (size_t)chg0 * 8192 + lane * 8;

    #pragma unroll 1
    for (int ch = 0; ch < 8; ch++) {
        const unsigned short* ab = ab0 + (size_t)ch * 8192;

        f32x4 acc[4];
        #pragma unroll
        for (int t = 0; t < 4; t++) acc[t] = (f32x4){0.f, 0.f, 0.f, 0.f};

        #pragma unroll
        for (int s = 0; s < 4; s++) {
            #pragma unroll
            for (int t = 0; t < 4; t++) {
                bf16x8 a = *(const bf16x8*)(ab + (s * 4 + t) * 512);
                acc[t] = __builtin_amdgcn_mfma_f32_16x16x32_bf16(a, bfr[s], acc[t], 0, 0, 0);
            }
        }

        // gather this lane's 16 values (all for feature row r0+col16)
        const int cbase = c0 + ch * 64;
        float s16[16];
        #pragma unroll
        for (int t = 0; t < 4; t++) {
            s16[t * 4 + 0] = acc[t][0];
            s16[t * 4 + 1] = acc[t][1];
            s16[t * 4 + 2] = acc[t][2];
            s16[t * 4 + 3] = acc[t][3];
        }
        if (msk) {
            #pragma unroll
            for (int t = 0; t < 4; t++) {
                int4 tc = *(const int4*)(target + cbase + t * 16 + quad * 4);
                if (tc.x == rtg) s16[t * 4 + 0] = -1e9f;
                if (tc.y == rtg) s16[t * 4 + 1] = -1e9f;
                if (tc.z == rtg) s16[t * 4 + 2] = -1e9f;
                if (tc.w == rtg) s16[t * 4 + 3] = -1e9f;
            }
        }

        sort16_desc(s16);
        if (ch == 0) {
            #pragma unroll
            for (int i = 0; i < 16; i++) lst[i] = s16[i];
        } else {
            float mg[16];
            #pragma unroll
            for (int i = 0; i < 16; i++) mg[i] = fmaxf(lst[i], s16[15 - i]);
            bitonic_clean16_desc(mg);
            #pragma unroll
            for (int i = 0; i < 16; i++) lst[i] = mg[i];
        }
    }

    // intra-wave merge across quads (lanes with same col16): 2 shfl levels
    #pragma unroll
    for (int off = 16; off <= 32; off <<= 1) {
        float mg[16];
        #pragma unroll
        for (int i = 0; i < 16; i++)
            mg[i] = fmaxf(lst[i], __shfl_xor(lst[15 - i], off, 64));
        bitonic_clean16_desc(mg);
        #pragma unroll
        for (int i = 0; i < 16; i++) lst[i] = mg[i];
    }

    if (lane < 16) {
        #pragma unroll
        for (int i = 0; i < 16; i++) tops[w][lane][i] = lst[i];
        tops[w][lane][16] = -3.0e38f;   // sentinel
    }
    __syncthreads();

    // cross-wave 4-way serial merge (waves cover disjoint candidate ranges)
    if (tid < 16) {
        int i0 = 0, i1 = 0, i2 = 0, i3 = 0;
        float* outp = topbuf + (((size_t)j * N + r0 + tid) * CSPLIT + cs) * KTOP;
        #pragma unroll
        for (int k = 0; k < KTOP; k++) {
            float v0 = tops[0][tid][i0], v1 = tops[1][tid][i1];
            float v2 = tops[2][tid][i2], v3 = tops[3][tid][i3];
            float m01 = fmaxf(v0, v1), m23 = fmaxf(v2, v3);
            float mx  = fmaxf(m01, m23);
            if      (mx == v0) i0++;
            else if (mx == v1) i1++;
            else if (mx == v2) i2++;
            else               i3++;
            outp[k] = mx;
        }
    }
}

// ---------------- finalize: 2-way merge of partials + entropy reduce ----------------
__global__ __launch_bounds__(64) void neguni_fin(
    const float* __restrict__ topbuf, float* __restrict__ out)
{
    __shared__ float buf[64][35];     // 2 lists of 17 (16 + sentinel) per thread
    __shared__ float mm[16][65];      // merged [row_l][k*4+j], padded

    const int t     = threadIdx.x;    // 0..63
    const int j     = t >> 4;         // 0..3
    const int row_l = t & 15;         // 0..15
    const int row   = blockIdx.x * 16 + row_l;

    const float4* src = (const float4*)(topbuf + ((size_t)j * N + row) * (CSPLIT * KTOP));
    #pragma unroll
    for (int q = 0; q < 8; q++) {
        float4 v = src[q];
        const int base = (q >> 2) * 17 + (q & 3) * 4;
        buf[t][base + 0] = v.x;
        buf[t][base + 1] = v.y;
        buf[t][base + 2] = v.z;
        buf[t][base + 3] = v.w;
    }
    buf[t][16] = -3.0e38f;
    buf[t][33] = -3.0e38f;

    {
        int ia = 0, ib = 17;
        #pragma unroll
        for (int k = 0; k < KTOP; k++) {
            float va = buf[t][ia], vb = buf[t][ib];
            bool ta = va >= vb;
            mm[row_l][k * 4 + j] = ta ? va : vb;
            if (ta) ia++; else ib++;
        }
    }
    __syncthreads();

    float val = 0.f;
    #pragma unroll
    for (int i = 0; i < 4; i++) {
        const int idx2 = t + i * 64;          // 0..255
        const int rl   = idx2 & 15;
        const int k    = idx2 >> 4;           // 0..15
        float l0 = mm[rl][k * 4 + 0] * 100.0f;
        float l1 = mm[rl][k * 4 + 1] * 100.0f;
        float l2 = mm[rl][k * 4 + 2] * 100.0f;
        float l3 = mm[rl][k * 4 + 3] * 100.0f;
        float m  = fmaxf(fmaxf(l0, l1), fmaxf(l2, l3));
        float d0 = l0 - m, d1 = l1 - m, d2 = l2 - m, d3 = l3 - m;
        float e0 = __expf(d0), e1 = __expf(d1), e2 = __expf(d2), e3 = __expf(d3);
        float s  = e0 + e1 + e2 + e3;
        float ent = (e0 * d0 + e1 * d1 + e2 * d2 + e3 * d3) / s - __logf(s);
        float dk  = __expf(-0.05129329439f * (float)k);   // 0.95^k
        val += ent * dk;
    }
    val *= (1.0f / (11.1974666f * (float)N));   // Ssum = (1-0.95^16)/0.05

    #pragma unroll
    for (int off = 32; off > 0; off >>= 1) val += __shfl_xor(val, off, 64);
    if (t == 0) {
        atomicAdd(out, val);
        if (blockIdx.x == 0) atomicAdd(out, 1.38629436112f);   // log(4)
    }
}

extern "C" void kernel_launch(void* const* d_in, const int* in_sizes, int n_in,
                              void* d_out, int out_size, void* d_ws, size_t ws_size,
                              hipStream_t stream) {
    const float* feat   = (const float*)d_in[0];
    const int*   target = (const int*)d_in[1];
    const float* negs   = (const float*)d_in[2];
    const int*   idxp   = (const int*)d_in[3];
    float* out = (float*)d_out;

    unsigned short* fh = (unsigned short*)d_ws;
    unsigned short* gh = fh + (size_t)N * D;                  // +1 MB
    float* topbuf      = (float*)(gh + (size_t)NJ * N * D);   // +5 MB, 2 MB long

    neguni_prep<<<dim3(512), dim3(256), 0, stream>>>(feat, negs, fh, gh, out);
    neguni_main<<<dim3(NJ * (N / 16) * CSPLIT), dim3(256), 0, stream>>>(fh, gh, target, idxp, topbuf);
    neguni_fin<<<dim3(N / 16), dim3(64), 0, stream>>>(topbuf, out);
}

// Round 3
// 133.092 us; speedup vs baseline: 1.0640x; 1.0082x over previous
//
#include <hip/hip_runtime.h>
#include <hip/hip_bf16.h>
#include <math.h>

#define N 4096
#define D 128
#define NJ 4
#define KTOP 16
#define CSPLIT 2

typedef __attribute__((ext_vector_type(8))) short bf16x8;
typedef __attribute__((ext_vector_type(4))) float f32x4;

// ws layout:
//   [0, 1MB)   fh   bf16 [N][D]       normalized feature rows, row-major
//   [1MB, 5MB) gh   bf16 [NJ][N*D]    normalized negative rows, FRAGMENT-MAJOR:
//              per j, per 64-cand chunk chg (64 chunks): 16 frags x 512 ushorts.
//   [5MB, 7MB) top  f32  [NJ][N][CSPLIT][16] partial sorted top-16 per col-split

__device__ __forceinline__ void ce_desc(float* a, int i, int l) {
    float x = a[i], y = a[l];
    a[i] = fmaxf(x, y);
    a[l] = fminf(x, y);
}

// Batcher odd-even mergesort of 16 (descending), 63 compare-exchanges.
// Harness-verified (absmax 0.0).
__device__ __forceinline__ void sort16_desc(float* a) {
    // sort(0,8)
    ce_desc(a,0,1);  ce_desc(a,2,3);  ce_desc(a,0,2);  ce_desc(a,1,3);  ce_desc(a,1,2);
    ce_desc(a,4,5);  ce_desc(a,6,7);  ce_desc(a,4,6);  ce_desc(a,5,7);  ce_desc(a,5,6);
    ce_desc(a,0,4);  ce_desc(a,2,6);  ce_desc(a,2,4);  ce_desc(a,1,5);  ce_desc(a,3,7);
    ce_desc(a,3,5);  ce_desc(a,1,2);  ce_desc(a,3,4);  ce_desc(a,5,6);
    // sort(8,8)
    ce_desc(a,8,9);  ce_desc(a,10,11); ce_desc(a,8,10); ce_desc(a,9,11); ce_desc(a,9,10);
    ce_desc(a,12,13); ce_desc(a,14,15); ce_desc(a,12,14); ce_desc(a,13,15); ce_desc(a,13,14);
    ce_desc(a,8,12); ce_desc(a,10,14); ce_desc(a,10,12); ce_desc(a,9,13); ce_desc(a,11,15);
    ce_desc(a,11,13); ce_desc(a,9,10); ce_desc(a,11,12); ce_desc(a,13,14);
    // oddEvenMerge(0,16,1)
    ce_desc(a,0,8);  ce_desc(a,4,12); ce_desc(a,4,8);  ce_desc(a,2,10); ce_desc(a,6,14);
    ce_desc(a,6,10); ce_desc(a,2,4);  ce_desc(a,6,8);  ce_desc(a,10,12);
    ce_desc(a,1,9);  ce_desc(a,5,13); ce_desc(a,5,9);  ce_desc(a,3,11); ce_desc(a,7,15);
    ce_desc(a,7,11); ce_desc(a,3,5);  ce_desc(a,7,9);  ce_desc(a,11,13);
    ce_desc(a,1,2);  ce_desc(a,3,4);  ce_desc(a,5,6);  ce_desc(a,7,8);  ce_desc(a,9,10);
    ce_desc(a,11,12); ce_desc(a,13,14);
}

// clean a bitonic 16-sequence into descending order (32 CE)
__device__ __forceinline__ void bitonic_clean16_desc(float* a) {
    #pragma unroll
    for (int jj = 8; jj > 0; jj >>= 1) {
        #pragma unroll
        for (int i = 0; i < 16; i++) {
            int l = i ^ jj;
            if (l > i) {
                float x = a[i], y = a[l];
                a[i] = fmaxf(x, y);
                a[l] = fminf(x, y);
            }
        }
    }
}

// ---------------- prep: fp32 L2-normalize -> bf16 (unchanged from R2) ----------------
__global__ __launch_bounds__(256) void neguni_prep(
    const float* __restrict__ feat, const float* __restrict__ negs,
    unsigned short* __restrict__ fh, unsigned short* __restrict__ gh,
    float* __restrict__ out)
{
    __shared__ unsigned short lbuf[8192];   // 16KB chunk staging

    if (blockIdx.x == 0 && threadIdx.x == 0) *out = 0.f;   // replaces memset dispatch

    if (blockIdx.x < 256) {
        const int w    = threadIdx.x >> 6;
        const int lane = threadIdx.x & 63;
        const int p    = lane & 15;
        const int rr   = lane >> 4;
        const int row  = blockIdx.x * 16 + w * 4 + rr;   // 0..4095

        const float* src = feat + (size_t)row * D;
        float4 v0 = ((const float4*)src)[p * 2];
        float4 v1 = ((const float4*)src)[p * 2 + 1];
        float ss = v0.x*v0.x + v0.y*v0.y + v0.z*v0.z + v0.w*v0.w
                 + v1.x*v1.x + v1.y*v1.y + v1.z*v1.z + v1.w*v1.w;
        ss += __shfl_xor(ss, 1, 64);
        ss += __shfl_xor(ss, 2, 64);
        ss += __shfl_xor(ss, 4, 64);
        ss += __shfl_xor(ss, 8, 64);
        const float inv = 1.0f / fmaxf(sqrtf(ss), 1e-12f);

        float f[8] = {v0.x, v0.y, v0.z, v0.w, v1.x, v1.y, v1.z, v1.w};
        unsigned int u[4];
        #pragma unroll
        for (int i = 0; i < 4; i++) {
            __hip_bfloat16 b0 = __float2bfloat16(f[2*i]   * inv);
            __hip_bfloat16 b1 = __float2bfloat16(f[2*i+1] * inv);
            u[i] = ((unsigned int)*(unsigned short*)&b1 << 16) | *(unsigned short*)&b0;
        }
        uint4 pk; pk.x = u[0]; pk.y = u[1]; pk.z = u[2]; pk.w = u[3];
        *(uint4*)(fh + (size_t)row * D + p * 8) = pk;
    } else {
        const int c   = blockIdx.x - 256;    // 0..255
        const int j   = c >> 6;
        const int chg = c & 63;
        const int t   = threadIdx.x;
        const int lr  = t >> 2;              // local row 0..63
        const int p4  = t & 3;               // 32-float piece within row

        const float* src = negs + ((size_t)(j * 4096 + chg * 64 + lr)) * D + p4 * 32;
        float4 v[8];
        float ss = 0.f;
        #pragma unroll
        for (int i = 0; i < 8; i++) {
            v[i] = ((const float4*)src)[i];
            ss += v[i].x*v[i].x + v[i].y*v[i].y + v[i].z*v[i].z + v[i].w*v[i].w;
        }
        ss += __shfl_xor(ss, 1, 64);
        ss += __shfl_xor(ss, 2, 64);
        const float inv = 1.0f / fmaxf(sqrtf(ss), 1e-12f);

        float f[32];
        #pragma unroll
        for (int i = 0; i < 8; i++) {
            f[4*i]   = v[i].x; f[4*i+1] = v[i].y;
            f[4*i+2] = v[i].z; f[4*i+3] = v[i].w;
        }

        const int t16 = lr >> 4;
        const int col = lr & 15;
        #pragma unroll
        for (int qq = 0; qq < 4; qq++) {
            unsigned int uu[4];
            #pragma unroll
            for (int h = 0; h < 4; h++) {
                __hip_bfloat16 b0 = __float2bfloat16(f[qq*8 + 2*h]     * inv);
                __hip_bfloat16 b1 = __float2bfloat16(f[qq*8 + 2*h + 1] * inv);
                uu[h] = ((unsigned int)*(unsigned short*)&b1 << 16) | *(unsigned short*)&b0;
            }
            uint4 pk; pk.x = uu[0]; pk.y = uu[1]; pk.z = uu[2]; pk.w = uu[3];
            *(uint4*)(lbuf + (p4 * 4 + t16) * 512 + (qq * 16 + col) * 8) = pk;
        }
        __syncthreads();

        uint4* dst = (uint4*)(gh + (size_t)j * N * D + (size_t)chg * 8192);
        const uint4* sb = (const uint4*)lbuf;
        dst[t]       = sb[t];
        dst[t + 256] = sb[t + 256];
        dst[t + 512] = sb[t + 512];
        dst[t + 768] = sb[t + 768];
    }
}

// ---------------- main: shared-A LDS double-buffer + MFMA + lane-local top-16 ----------------
// Block = (j, 64-row tile, cs). 4 waves x 16 rows; all waves share the SAME
// candidate chunk each iteration (A-fragments staged ONCE per block into LDS via
// global_load_lds, double-buffered -> load latency hidden under the sort, zero
// VGPR cost, and 4x less L2 traffic than per-wave private loads).
// Each wave covers its 16 rows x all 2048 cands -> writes topbuf directly.
__global__ __launch_bounds__(256, 2) void neguni_main(
    const unsigned short* __restrict__ fh, const unsigned short* __restrict__ gh,
    const int* __restrict__ target, const int* __restrict__ idxp,
    float* __restrict__ topbuf)
{
    __shared__ unsigned short lbuf[2][8192];   // 2 x 16KB A-chunk double buffer

    const int tid   = threadIdx.x;
    const int w     = tid >> 6;
    const int lane  = tid & 63;
    const int col16 = lane & 15;     // feature row within wave's 16
    const int quad  = lane >> 4;

    const int j   = blockIdx.x & 3;
    const int ft  = (blockIdx.x >> 2) & 63;
    const int cs  = blockIdx.x >> 8;
    const int r0  = ft * 64;
    const int row = r0 + w * 16 + col16;
    const int c0  = cs * 2048;
    const int idx = idxp[0];
    const bool msk = (j == idx);

    // B fragments: this wave's 16 feature rows, persistent in VGPRs
    bf16x8 bfr[4];
    {
        const unsigned short* fr = fh + (size_t)row * D + quad * 8;
        bfr[0] = *(const bf16x8*)(fr);
        bfr[1] = *(const bf16x8*)(fr + 32);
        bfr[2] = *(const bf16x8*)(fr + 64);
        bfr[3] = *(const bf16x8*)(fr + 96);
    }
    const int rtg = target[row];

    // candidate-range base in gh (fragment-major, 16KB per 64-cand chunk)
    const unsigned short* gcs = gh + (size_t)j * N * D + (size_t)cs * 32 * 8192;

    float lst[KTOP];

    // ---- stage chunk 0 into buffer 0 (4 x 1KB DMA per wave; lds dest wave-uniform) ----
    {
        const unsigned short* gsrc = gcs + w * 2048 + lane * 8;
        unsigned short* ldst = &lbuf[0][w * 2048];
        #pragma unroll
        for (int i = 0; i < 4; i++) {
            __builtin_amdgcn_global_load_lds(
                (const __attribute__((address_space(1))) void*)(gsrc + i * 512),
                (__attribute__((address_space(3))) void*)(ldst + i * 512),
                16, 0, 0);
        }
    }

    #pragma unroll 1
    for (int ch = 0; ch < 32; ch++) {
        __syncthreads();   // implicit vmcnt(0): buf[ch&1] staged; prev reads done

        // issue next chunk's DMA into the other buffer (hidden under this compute)
        if (ch < 31) {
            const unsigned short* gsrc = gcs + (size_t)(ch + 1) * 8192 + w * 2048 + lane * 8;
            unsigned short* ldst = &lbuf[(ch + 1) & 1][w * 2048];
            #pragma unroll
            for (int i = 0; i < 4; i++) {
                __builtin_amdgcn_global_load_lds(
                    (const __attribute__((address_space(1))) void*)(gsrc + i * 512),
                    (__attribute__((address_space(3))) void*)(ldst + i * 512),
                    16, 0, 0);
            }
        }

        // ---- compute from current buffer: 16 ds_read_b128 + 16 MFMA ----
        const unsigned short* lb = &lbuf[ch & 1][0];
        f32x4 acc[4];
        #pragma unroll
        for (int t = 0; t < 4; t++) acc[t] = (f32x4){0.f, 0.f, 0.f, 0.f};
        #pragma unroll
        for (int s = 0; s < 4; s++) {
            #pragma unroll
            for (int t = 0; t < 4; t++) {
                bf16x8 a = *(const bf16x8*)(lb + (s * 4 + t) * 512 + lane * 8);
                acc[t] = __builtin_amdgcn_mfma_f32_16x16x32_bf16(a, bfr[s], acc[t], 0, 0, 0);
            }
        }

        // ---- gather + mask + sort + merge ----
        const int cbase = c0 + ch * 64;
        float s16[16];
        #pragma unroll
        for (int t = 0; t < 4; t++) {
            s16[t * 4 + 0] = acc[t][0];
            s16[t * 4 + 1] = acc[t][1];
            s16[t * 4 + 2] = acc[t][2];
            s16[t * 4 + 3] = acc[t][3];
        }
        if (msk) {
            #pragma unroll
            for (int t = 0; t < 4; t++) {
                int4 tc = *(const int4*)(target + cbase + t * 16 + quad * 4);
                if (tc.x == rtg) s16[t * 4 + 0] = -1e9f;
                if (tc.y == rtg) s16[t * 4 + 1] = -1e9f;
                if (tc.z == rtg) s16[t * 4 + 2] = -1e9f;
                if (tc.w == rtg) s16[t * 4 + 3] = -1e9f;
            }
        }

        sort16_desc(s16);
        if (ch == 0) {
            #pragma unroll
            for (int i = 0; i < 16; i++) lst[i] = s16[i];
        } else {
            // in-place bitonic merge: top-16 of (lst desc, s16 desc)
            #pragma unroll
            for (int i = 0; i < 16; i++) lst[i] = fmaxf(lst[i], s16[15 - i]);
            bitonic_clean16_desc(lst);
        }
    }

    // intra-wave merge across quads (lanes with same col16): 2 shfl levels
    #pragma unroll
    for (int off = 16; off <= 32; off <<= 1) {
        float mg[16];
        #pragma unroll
        for (int i = 0; i < 16; i++)
            mg[i] = fmaxf(lst[i], __shfl_xor(lst[15 - i], off, 64));
        bitonic_clean16_desc(mg);
        #pragma unroll
        for (int i = 0; i < 16; i++) lst[i] = mg[i];
    }

    // each wave owns its 16 rows completely: write directly (no cross-wave merge)
    if (quad == 0) {
        float* outp = topbuf + (((size_t)j * N + r0 + w * 16 + col16) * CSPLIT + cs) * KTOP;
        #pragma unroll
        for (int k = 0; k < KTOP; k++) outp[k] = lst[k];
    }
}

// ---------------- finalize: 2-way merge of partials + entropy reduce (unchanged) ----------------
__global__ __launch_bounds__(64) void neguni_fin(
    const float* __restrict__ topbuf, float* __restrict__ out)
{
    __shared__ float buf[64][35];
    __shared__ float mm[16][65];

    const int t     = threadIdx.x;    // 0..63
    const int j     = t >> 4;         // 0..3
    const int row_l = t & 15;         // 0..15
    const int row   = blockIdx.x * 16 + row_l;

    const float4* src = (const float4*)(topbuf + ((size_t)j * N + row) * (CSPLIT * KTOP));
    #pragma unroll
    for (int q = 0; q < 8; q++) {
        float4 v = src[q];
        const int base = (q >> 2) * 17 + (q & 3) * 4;
        buf[t][base + 0] = v.x;
        buf[t][base + 1] = v.y;
        buf[t][base + 2] = v.z;
        buf[t][base + 3] = v.w;
    }
    buf[t][16] = -3.0e38f;
    buf[t][33] = -3.0e38f;

    {
        int ia = 0, ib = 17;
        #pragma unroll
        for (int k = 0; k < KTOP; k++) {
            float va = buf[t][ia], vb = buf[t][ib];
            bool ta = va >= vb;
            mm[row_l][k * 4 + j] = ta ? va : vb;
            if (ta) ia++; else ib++;
        }
    }
    __syncthreads();

    float val = 0.f;
    #pragma unroll
    for (int i = 0; i < 4; i++) {
        const int idx2 = t + i * 64;          // 0..255
        const int rl   = idx2 & 15;
        const int k    = idx2 >> 4;           // 0..15
        float l0 = mm[rl][k * 4 + 0] * 100.0f;
        float l1 = mm[rl][k * 4 + 1] * 100.0f;
        float l2 = mm[rl][k * 4 + 2] * 100.0f;
        float l3 = mm[rl][k * 4 + 3] * 100.0f;
        float m  = fmaxf(fmaxf(l0, l1), fmaxf(l2, l3));
        float d0 = l0 - m, d1 = l1 - m, d2 = l2 - m, d3 = l3 - m;
        float e0 = __expf(d0), e1 = __expf(d1), e2 = __expf(d2), e3 = __expf(d3);
        float s  = e0 + e1 + e2 + e3;
        float ent = (e0 * d0 + e1 * d1 + e2 * d2 + e3 * d3) / s - __logf(s);
        float dk  = __expf(-0.05129329439f * (float)k);   // 0.95^k
        val += ent * dk;
    }
    val *= (1.0f / (11.1974666f * (float)N));   // Ssum = (1-0.95^16)/0.05

    #pragma unroll
    for (int off = 32; off > 0; off >>= 1) val += __shfl_xor(val, off, 64);
    if (t == 0) {
        atomicAdd(out, val);
        if (blockIdx.x == 0) atomicAdd(out, 1.38629436112f);   // log(4)
    }
}

extern "C" void kernel_launch(void* const* d_in, const int* in_sizes, int n_in,
                              void* d_out, int out_size, void* d_ws, size_t ws_size,
                              hipStream_t stream) {
    const float* feat   = (const float*)d_in[0];
    const int*   target = (const int*)d_in[1];
    const float* negs   = (const float*)d_in[2];
    const int*   idxp   = (const int*)d_in[3];
    float* out = (float*)d_out;

    unsigned short* fh = (unsigned short*)d_ws;
    unsigned short* gh = fh + (size_t)N * D;                  // +1 MB
    float* topbuf      = (float*)(gh + (size_t)NJ * N * D);   // +5 MB, 2 MB long

    neguni_prep<<<dim3(512), dim3(256), 0, stream>>>(feat, negs, fh, gh, out);
    neguni_main<<<dim3(NJ * (N / 64) * CSPLIT), dim3(256), 0, stream>>>(fh, gh, target, idxp, topbuf);
    neguni_fin<<<dim3(N / 16), dim3(64), 0, stream>>>(topbuf, out);
}

// Round 4
// 126.931 us; speedup vs baseline: 1.1157x; 1.0485x over previous
//
#include <hip/hip_runtime.h>
#include <hip/hip_bf16.h>
#include <math.h>

#define N 4096
#define D 128
#define NJ 4
#define KTOP 16

typedef __attribute__((ext_vector_type(8))) short bf16x8;
typedef __attribute__((ext_vector_type(4))) float f32x4;

// ws layout (ncs = 4 when ws >= 9MB, else 2):
//   [0, 1MB)   fh   bf16 [N][D]       normalized feature rows, row-major
//   [1MB, 5MB) gh   bf16 [NJ][N*D]    normalized negative rows, FRAGMENT-MAJOR:
//              per j, per 64-cand chunk chg (64 chunks): 16 frags x 512 ushorts.
//   [5MB, ..)  top  f32  [NJ][N][ncs][16] partial sorted top-16 per col-split

__device__ __forceinline__ void ce_desc(float* a, int i, int l) {
    float x = a[i], y = a[l];
    a[i] = fmaxf(x, y);
    a[l] = fminf(x, y);
}

// Batcher odd-even mergesort of 16 (descending), 63 compare-exchanges.
// Harness-verified (absmax 0.0).
__device__ __forceinline__ void sort16_desc(float* a) {
    // sort(0,8)
    ce_desc(a,0,1);  ce_desc(a,2,3);  ce_desc(a,0,2);  ce_desc(a,1,3);  ce_desc(a,1,2);
    ce_desc(a,4,5);  ce_desc(a,6,7);  ce_desc(a,4,6);  ce_desc(a,5,7);  ce_desc(a,5,6);
    ce_desc(a,0,4);  ce_desc(a,2,6);  ce_desc(a,2,4);  ce_desc(a,1,5);  ce_desc(a,3,7);
    ce_desc(a,3,5);  ce_desc(a,1,2);  ce_desc(a,3,4);  ce_desc(a,5,6);
    // sort(8,8)
    ce_desc(a,8,9);  ce_desc(a,10,11); ce_desc(a,8,10); ce_desc(a,9,11); ce_desc(a,9,10);
    ce_desc(a,12,13); ce_desc(a,14,15); ce_desc(a,12,14); ce_desc(a,13,15); ce_desc(a,13,14);
    ce_desc(a,8,12); ce_desc(a,10,14); ce_desc(a,10,12); ce_desc(a,9,13); ce_desc(a,11,15);
    ce_desc(a,11,13); ce_desc(a,9,10); ce_desc(a,11,12); ce_desc(a,13,14);
    // oddEvenMerge(0,16,1)
    ce_desc(a,0,8);  ce_desc(a,4,12); ce_desc(a,4,8);  ce_desc(a,2,10); ce_desc(a,6,14);
    ce_desc(a,6,10); ce_desc(a,2,4);  ce_desc(a,6,8);  ce_desc(a,10,12);
    ce_desc(a,1,9);  ce_desc(a,5,13); ce_desc(a,5,9);  ce_desc(a,3,11); ce_desc(a,7,15);
    ce_desc(a,7,11); ce_desc(a,3,5);  ce_desc(a,7,9);  ce_desc(a,11,13);
    ce_desc(a,1,2);  ce_desc(a,3,4);  ce_desc(a,5,6);  ce_desc(a,7,8);  ce_desc(a,9,10);
    ce_desc(a,11,12); ce_desc(a,13,14);
}

// clean a bitonic 16-sequence into descending order (32 CE)
__device__ __forceinline__ void bitonic_clean16_desc(float* a) {
    #pragma unroll
    for (int jj = 8; jj > 0; jj >>= 1) {
        #pragma unroll
        for (int i = 0; i < 16; i++) {
            int l = i ^ jj;
            if (l > i) {
                float x = a[i], y = a[l];
                a[i] = fmaxf(x, y);
                a[l] = fminf(x, y);
            }
        }
    }
}

// ---------------- prep: fp32 L2-normalize -> bf16 (unchanged from R3) ----------------
__global__ __launch_bounds__(256) void neguni_prep(
    const float* __restrict__ feat, const float* __restrict__ negs,
    unsigned short* __restrict__ fh, unsigned short* __restrict__ gh,
    float* __restrict__ out)
{
    __shared__ unsigned short lbuf[8192];   // 16KB chunk staging

    if (blockIdx.x == 0 && threadIdx.x == 0) *out = 0.f;   // replaces memset dispatch

    if (blockIdx.x < 256) {
        const int w    = threadIdx.x >> 6;
        const int lane = threadIdx.x & 63;
        const int p    = lane & 15;
        const int rr   = lane >> 4;
        const int row  = blockIdx.x * 16 + w * 4 + rr;   // 0..4095

        const float* src = feat + (size_t)row * D;
        float4 v0 = ((const float4*)src)[p * 2];
        float4 v1 = ((const float4*)src)[p * 2 + 1];
        float ss = v0.x*v0.x + v0.y*v0.y + v0.z*v0.z + v0.w*v0.w
                 + v1.x*v1.x + v1.y*v1.y + v1.z*v1.z + v1.w*v1.w;
        ss += __shfl_xor(ss, 1, 64);
        ss += __shfl_xor(ss, 2, 64);
        ss += __shfl_xor(ss, 4, 64);
        ss += __shfl_xor(ss, 8, 64);
        const float inv = 1.0f / fmaxf(sqrtf(ss), 1e-12f);

        float f[8] = {v0.x, v0.y, v0.z, v0.w, v1.x, v1.y, v1.z, v1.w};
        unsigned int u[4];
        #pragma unroll
        for (int i = 0; i < 4; i++) {
            __hip_bfloat16 b0 = __float2bfloat16(f[2*i]   * inv);
            __hip_bfloat16 b1 = __float2bfloat16(f[2*i+1] * inv);
            u[i] = ((unsigned int)*(unsigned short*)&b1 << 16) | *(unsigned short*)&b0;
        }
        uint4 pk; pk.x = u[0]; pk.y = u[1]; pk.z = u[2]; pk.w = u[3];
        *(uint4*)(fh + (size_t)row * D + p * 8) = pk;
    } else {
        const int c   = blockIdx.x - 256;    // 0..255
        const int j   = c >> 6;
        const int chg = c & 63;
        const int t   = threadIdx.x;
        const int lr  = t >> 2;              // local row 0..63
        const int p4  = t & 3;               // 32-float piece within row

        const float* src = negs + ((size_t)(j * 4096 + chg * 64 + lr)) * D + p4 * 32;
        float4 v[8];
        float ss = 0.f;
        #pragma unroll
        for (int i = 0; i < 8; i++) {
            v[i] = ((const float4*)src)[i];
            ss += v[i].x*v[i].x + v[i].y*v[i].y + v[i].z*v[i].z + v[i].w*v[i].w;
        }
        ss += __shfl_xor(ss, 1, 64);
        ss += __shfl_xor(ss, 2, 64);
        const float inv = 1.0f / fmaxf(sqrtf(ss), 1e-12f);

        float f[32];
        #pragma unroll
        for (int i = 0; i < 8; i++) {
            f[4*i]   = v[i].x; f[4*i+1] = v[i].y;
            f[4*i+2] = v[i].z; f[4*i+3] = v[i].w;
        }

        const int t16 = lr >> 4;
        const int col = lr & 15;
        #pragma unroll
        for (int qq = 0; qq < 4; qq++) {
            unsigned int uu[4];
            #pragma unroll
            for (int h = 0; h < 4; h++) {
                __hip_bfloat16 b0 = __float2bfloat16(f[qq*8 + 2*h]     * inv);
                __hip_bfloat16 b1 = __float2bfloat16(f[qq*8 + 2*h + 1] * inv);
                uu[h] = ((unsigned int)*(unsigned short*)&b1 << 16) | *(unsigned short*)&b0;
            }
            uint4 pk; pk.x = uu[0]; pk.y = uu[1]; pk.z = uu[2]; pk.w = uu[3];
            *(uint4*)(lbuf + (p4 * 4 + t16) * 512 + (qq * 16 + col) * 8) = pk;
        }
        __syncthreads();

        uint4* dst = (uint4*)(gh + (size_t)j * N * D + (size_t)chg * 8192);
        const uint4* sb = (const uint4*)lbuf;
        dst[t]       = sb[t];
        dst[t + 256] = sb[t + 256];
        dst[t + 512] = sb[t + 512];
        dst[t + 768] = sb[t + 768];
    }
}

// ---------------- main: shared-A LDS double-buffer + MFMA + lane-local top-16 ----------------
// R3 structure, but candidate range split ncs ways (runtime 4 when ws allows):
// grid = NJ * 64 * ncs blocks -> 4 blocks/CU at ncs=4 = 16 waves/CU = 4 waves/SIMD,
// double the wave pool that R3 had (2/SIMD) to fill the per-chunk stall holes.
// LDS 32KB/block x 4 blocks = 128KB <= 160KB. DMA + LDS traffic totals unchanged.
__global__ __launch_bounds__(256, 4) void neguni_main(
    const unsigned short* __restrict__ fh, const unsigned short* __restrict__ gh,
    const int* __restrict__ target, const int* __restrict__ idxp,
    float* __restrict__ topbuf, int ncs, int nch)
{
    __shared__ unsigned short lbuf[2][8192];   // 2 x 16KB A-chunk double buffer

    const int tid   = threadIdx.x;
    const int w     = tid >> 6;
    const int lane  = tid & 63;
    const int col16 = lane & 15;     // feature row within wave's 16
    const int quad  = lane >> 4;

    const int j   = blockIdx.x & 3;
    const int ft  = (blockIdx.x >> 2) & 63;
    const int cs  = blockIdx.x >> 8;
    const int r0  = ft * 64;
    const int row = r0 + w * 16 + col16;
    const int c0  = cs * nch * 64;
    const int idx = idxp[0];
    const bool msk = (j == idx);

    // B fragments: this wave's 16 feature rows, persistent in VGPRs
    bf16x8 bfr[4];
    {
        const unsigned short* fr = fh + (size_t)row * D + quad * 8;
        bfr[0] = *(const bf16x8*)(fr);
        bfr[1] = *(const bf16x8*)(fr + 32);
        bfr[2] = *(const bf16x8*)(fr + 64);
        bfr[3] = *(const bf16x8*)(fr + 96);
    }
    const int rtg = target[row];

    // candidate-range base in gh (fragment-major, 16KB per 64-cand chunk)
    const unsigned short* gcs = gh + (size_t)j * N * D + (size_t)cs * nch * 8192;

    float lst[KTOP];

    // ---- stage chunk 0 into buffer 0 (4 x 1KB DMA per wave; lds dest wave-uniform) ----
    {
        const unsigned short* gsrc = gcs + w * 2048 + lane * 8;
        unsigned short* ldst = &lbuf[0][w * 2048];
        #pragma unroll
        for (int i = 0; i < 4; i++) {
            __builtin_amdgcn_global_load_lds(
                (const __attribute__((address_space(1))) void*)(gsrc + i * 512),
                (__attribute__((address_space(3))) void*)(ldst + i * 512),
                16, 0, 0);
        }
    }

    #pragma unroll 1
    for (int ch = 0; ch < nch; ch++) {
        __syncthreads();   // implicit vmcnt(0): buf[ch&1] staged; prev reads done

        // issue next chunk's DMA into the other buffer (hidden under this compute)
        if (ch < nch - 1) {
            const unsigned short* gsrc = gcs + (size_t)(ch + 1) * 8192 + w * 2048 + lane * 8;
            unsigned short* ldst = &lbuf[(ch + 1) & 1][w * 2048];
            #pragma unroll
            for (int i = 0; i < 4; i++) {
                __builtin_amdgcn_global_load_lds(
                    (const __attribute__((address_space(1))) void*)(gsrc + i * 512),
                    (__attribute__((address_space(3))) void*)(ldst + i * 512),
                    16, 0, 0);
            }
        }

        // ---- compute from current buffer: 16 ds_read_b128 + 16 MFMA ----
        const unsigned short* lb = &lbuf[ch & 1][0];
        f32x4 acc[4];
        #pragma unroll
        for (int t = 0; t < 4; t++) acc[t] = (f32x4){0.f, 0.f, 0.f, 0.f};
        #pragma unroll
        for (int s = 0; s < 4; s++) {
            #pragma unroll
            for (int t = 0; t < 4; t++) {
                bf16x8 a = *(const bf16x8*)(lb + (s * 4 + t) * 512 + lane * 8);
                acc[t] = __builtin_amdgcn_mfma_f32_16x16x32_bf16(a, bfr[s], acc[t], 0, 0, 0);
            }
        }

        // ---- gather + mask + sort + merge ----
        const int cbase = c0 + ch * 64;
        float s16[16];
        #pragma unroll
        for (int t = 0; t < 4; t++) {
            s16[t * 4 + 0] = acc[t][0];
            s16[t * 4 + 1] = acc[t][1];
            s16[t * 4 + 2] = acc[t][2];
            s16[t * 4 + 3] = acc[t][3];
        }
        if (msk) {
            #pragma unroll
            for (int t = 0; t < 4; t++) {
                int4 tc = *(const int4*)(target + cbase + t * 16 + quad * 4);
                if (tc.x == rtg) s16[t * 4 + 0] = -1e9f;
                if (tc.y == rtg) s16[t * 4 + 1] = -1e9f;
                if (tc.z == rtg) s16[t * 4 + 2] = -1e9f;
                if (tc.w == rtg) s16[t * 4 + 3] = -1e9f;
            }
        }

        sort16_desc(s16);
        if (ch == 0) {
            #pragma unroll
            for (int i = 0; i < 16; i++) lst[i] = s16[i];
        } else {
            // in-place bitonic merge: top-16 of (lst desc, s16 desc)
            #pragma unroll
            for (int i = 0; i < 16; i++) lst[i] = fmaxf(lst[i], s16[15 - i]);
            bitonic_clean16_desc(lst);
        }
    }

    // intra-wave merge across quads (lanes with same col16): 2 shfl levels
    #pragma unroll
    for (int off = 16; off <= 32; off <<= 1) {
        float mg[16];
        #pragma unroll
        for (int i = 0; i < 16; i++)
            mg[i] = fmaxf(lst[i], __shfl_xor(lst[15 - i], off, 64));
        bitonic_clean16_desc(mg);
        #pragma unroll
        for (int i = 0; i < 16; i++) lst[i] = mg[i];
    }

    // each wave owns its 16 rows completely: write directly (no cross-wave merge)
    if (quad == 0) {
        float* outp = topbuf + (((size_t)j * N + row) * ncs + cs) * KTOP;
        #pragma unroll
        for (int k = 0; k < KTOP; k++) outp[k] = lst[k];
    }
}

// ---------------- finalize: generic 4-way merge of partials + entropy reduce ----------------
// Handles ncs = 2 or 4: unused lists get a head sentinel and are never picked
// (real lists hold >= 32 values, we only pick 16).
__global__ __launch_bounds__(64) void neguni_fin(
    const float* __restrict__ topbuf, float* __restrict__ out, int ncs)
{
    __shared__ float buf[64][69];     // 4 lists x (16 + sentinel) per thread
    __shared__ float mm[16][65];      // merged [row_l][k*4+j], padded

    const int t     = threadIdx.x;    // 0..63
    const int j     = t >> 4;         // 0..3
    const int row_l = t & 15;         // 0..15
    const int row   = blockIdx.x * 16 + row_l;

    #pragma unroll
    for (int c = 0; c < 4; c++) {
        if (c < ncs) {
            const float4* src = (const float4*)(topbuf + (((size_t)j * N + row) * ncs + c) * KTOP);
            #pragma unroll
            for (int q = 0; q < 4; q++) {
                float4 v = src[q];
                buf[t][c * 17 + q * 4 + 0] = v.x;
                buf[t][c * 17 + q * 4 + 1] = v.y;
                buf[t][c * 17 + q * 4 + 2] = v.z;
                buf[t][c * 17 + q * 4 + 3] = v.w;
            }
        } else {
            buf[t][c * 17] = -3.0e38f;   // head sentinel: list never picked
        }
        buf[t][c * 17 + 16] = -3.0e38f;  // tail sentinel
    }

    {
        int i0 = 0, i1 = 17, i2 = 34, i3 = 51;
        #pragma unroll
        for (int k = 0; k < KTOP; k++) {
            float v0 = buf[t][i0], v1 = buf[t][i1];
            float v2 = buf[t][i2], v3 = buf[t][i3];
            float m01 = fmaxf(v0, v1), m23 = fmaxf(v2, v3);
            float mx  = fmaxf(m01, m23);
            if      (mx == v0) i0++;
            else if (mx == v1) i1++;
            else if (mx == v2) i2++;
            else               i3++;
            mm[row_l][k * 4 + j] = mx;
        }
    }
    __syncthreads();

    float val = 0.f;
    #pragma unroll
    for (int i = 0; i < 4; i++) {
        const int idx2 = t + i * 64;          // 0..255
        const int rl   = idx2 & 15;
        const int k    = idx2 >> 4;           // 0..15
        float l0 = mm[rl][k * 4 + 0] * 100.0f;
        float l1 = mm[rl][k * 4 + 1] * 100.0f;
        float l2 = mm[rl][k * 4 + 2] * 100.0f;
        float l3 = mm[rl][k * 4 + 3] * 100.0f;
        float m  = fmaxf(fmaxf(l0, l1), fmaxf(l2, l3));
        float d0 = l0 - m, d1 = l1 - m, d2 = l2 - m, d3 = l3 - m;
        float e0 = __expf(d0), e1 = __expf(d1), e2 = __expf(d2), e3 = __expf(d3);
        float s  = e0 + e1 + e2 + e3;
        float ent = (e0 * d0 + e1 * d1 + e2 * d2 + e3 * d3) / s - __logf(s);
        float dk  = __expf(-0.05129329439f * (float)k);   // 0.95^k
        val += ent * dk;
    }
    val *= (1.0f / (11.1974666f * (float)N));   // Ssum = (1-0.95^16)/0.05

    #pragma unroll
    for (int off = 32; off > 0; off >>= 1) val += __shfl_xor(val, off, 64);
    if (t == 0) {
        atomicAdd(out, val);
        if (blockIdx.x == 0) atomicAdd(out, 1.38629436112f);   // log(4)
    }
}

extern "C" void kernel_launch(void* const* d_in, const int* in_sizes, int n_in,
                              void* d_out, int out_size, void* d_ws, size_t ws_size,
                              hipStream_t stream) {
    const float* feat   = (const float*)d_in[0];
    const int*   target = (const int*)d_in[1];
    const float* negs   = (const float*)d_in[2];
    const int*   idxp   = (const int*)d_in[3];
    float* out = (float*)d_out;

    unsigned short* fh = (unsigned short*)d_ws;
    unsigned short* gh = fh + (size_t)N * D;                  // +1 MB
    float* topbuf      = (float*)(gh + (size_t)NJ * N * D);   // +5 MB

    // ncs=4 needs 1MB(fh) + 4MB(gh) + 4MB(topbuf) = 9MB workspace; fall back to 2.
    const int ncs = (ws_size >= (size_t)9 * 1024 * 1024) ? 4 : 2;
    const int nch = 64 / ncs;   // 64-cand chunks per block

    neguni_prep<<<dim3(512), dim3(256), 0, stream>>>(feat, negs, fh, gh, out);
    neguni_main<<<dim3(NJ * 64 * ncs), dim3(256), 0, stream>>>(fh, gh, target, idxp, topbuf, ncs, nch);
    neguni_fin<<<dim3(N / 16), dim3(64), 0, stream>>>(topbuf, out, ncs);
}